// Round 7
// baseline (422.850 us; speedup 1.0000x reference)
//
#include <hip/hip_runtime.h>
#include <hip/hip_bf16.h>

#define L_DIM 384
#define DPC 128
#define NH 4
#define DHD 32
#define HD 128
#define NROWS (L_DIM*L_DIM)
#define NSPLIT 8

typedef __hip_bfloat16 bf16;
typedef __attribute__((ext_vector_type(8))) short bf8_t;   // 8 bf16 (4 VGPRs)
typedef __attribute__((ext_vector_type(4))) short bf4_t;   // 4 bf16 (2 VGPRs)
typedef __attribute__((ext_vector_type(4))) float f4_t;

__device__ __forceinline__ float bf2f(bf16 x){ return __bfloat162float(x); }
__device__ __forceinline__ bf16 f2bf(float x){ return __float2bfloat16(x); }

union bfu8 { bf8_t v; bf16 h[8]; };
union bfu2 { unsigned u; bf16 h[2]; };

// ---------------------------------------------------------------------------
// Kernel 0: f32 weights -> fragment-major bf16 packs.
__global__ __launch_bounds__(256) void k_prep(
    const float* __restrict__ Wq, const float* __restrict__ Wk, const float* __restrict__ Wv,
    const float* __restrict__ Wg, const float* __restrict__ Wo,
    bf16* __restrict__ Wqp, bf16* __restrict__ Wkp, bf16* __restrict__ Wvp,
    bf16* __restrict__ Wgp, bf16* __restrict__ Wop)
{
  const int o = blockIdx.x * 256 + threadIdx.x;   // 64 blocks -> 16384
  const int j = o & 7, lane = (o >> 3) & 63, ks = (o >> 9) & 3, nt = o >> 11;
  const int src = (nt*16 + (lane & 15))*DPC + ks*32 + (lane >> 4)*8 + j;
  Wqp[o] = f2bf(Wq[src]);
  Wkp[o] = f2bf(Wk[src]);
  Wvp[o] = f2bf(Wv[src]);
  Wgp[o] = f2bf(Wg[src]);
  Wop[o] = f2bf(Wo[src]);
}

// ---------------------------------------------------------------------------
// Kernel 1 (MERGED): bias-projection blocks + pair-projection blocks in ONE
// launch, interleaved 2:1 by blockIdx%3 so every CU hosts both types.
// Bias blocks are read-dominated (75.5 MB fetch, no LDS/MFMA); pair blocks
// are write-dominated (151 MB store). Overlapping them fills both memory
// directions that each kernel alone left idle. Both paths are verbatim
// copies of the proven round-0/6 kernels; branch is block-uniform.
__global__ __launch_bounds__(256) void k_ln_proj(
    const float* __restrict__ pair, const float* __restrict__ lnpg, const float* __restrict__ lnpb,
    const float* __restrict__ bias, const float* __restrict__ lnbg, const float* __restrict__ lnbb,
    const float* __restrict__ Wb,
    const bf16* __restrict__ Wqp, const bf16* __restrict__ Wkp, const bf16* __restrict__ Wvp,
    const bf16* __restrict__ Wgp, const float* __restrict__ bg,
    bf16* __restrict__ qf, bf16* __restrict__ kf, bf16* __restrict__ vf, bf16* __restrict__ gatef,
    float* __restrict__ bscore)
{
  __shared__ __align__(16) bf16 Sh[5120 + 3*4352];   // pair path only
  const int bid = blockIdx.x;
  const int ty = bid % 3;
  const int tid = threadIdx.x;
  const int wave = tid >> 6, lane = tid & 63;

  if (ty < 2) {
    // =======================  BIAS PATH (k_bias_proj)  =====================
    const int bblk = (bid / 3) * 2 + ty;               // 0..9215
    const int sub = lane >> 4, l16 = lane & 15, c = l16 * 8;
    const int t = bblk * 16 + wave * 4 + sub;          // memory row of bias
    const int j = t / L_DIM, i = t % L_DIM;            // bsrc[i][j] = bias row t

    const float4 ga = *(const float4*)&lnbg[c], gb = *(const float4*)&lnbg[c+4];
    const float4 ba = *(const float4*)&lnbb[c], bb = *(const float4*)&lnbb[c+4];
    const float4 xa = *(const float4*)&bias[(size_t)t * DPC + c];
    const float4 xb = *(const float4*)&bias[(size_t)t * DPC + c + 4];

    float s  = xa.x+xa.y+xa.z+xa.w + xb.x+xb.y+xb.z+xb.w;
    float ss = xa.x*xa.x+xa.y*xa.y+xa.z*xa.z+xa.w*xa.w
             + xb.x*xb.x+xb.y*xb.y+xb.z*xb.z+xb.w*xb.w;
    #pragma unroll
    for (int off = 8; off; off >>= 1) { s += __shfl_xor(s, off, 64); ss += __shfl_xor(ss, off, 64); }
    const float mean = s * (1.f/128.f);
    const float var  = ss * (1.f/128.f) - mean*mean;
    const float rstd = rsqrtf(var + 1e-5f);
    float y[8];
    y[0]=(xa.x-mean)*rstd*ga.x+ba.x; y[1]=(xa.y-mean)*rstd*ga.y+ba.y;
    y[2]=(xa.z-mean)*rstd*ga.z+ba.z; y[3]=(xa.w-mean)*rstd*ga.w+ba.w;
    y[4]=(xb.x-mean)*rstd*gb.x+bb.x; y[5]=(xb.y-mean)*rstd*gb.y+bb.y;
    y[6]=(xb.z-mean)*rstd*gb.z+bb.z; y[7]=(xb.w-mean)*rstd*gb.w+bb.w;

    float p[4];
    #pragma unroll
    for (int h = 0; h < 4; ++h) {
      const float4 wa = *(const float4*)&Wb[h*DPC + c];
      const float4 wb4 = *(const float4*)&Wb[h*DPC + c + 4];
      p[h] = y[0]*wa.x + y[1]*wa.y + y[2]*wa.z + y[3]*wa.w
           + y[4]*wb4.x + y[5]*wb4.y + y[6]*wb4.z + y[7]*wb4.w;
      #pragma unroll
      for (int off = 8; off; off >>= 1) p[h] += __shfl_xor(p[h], off, 64);
    }
    if (l16 == 0) {
      #pragma unroll
      for (int h = 0; h < 4; ++h)
        bscore[((size_t)h*L_DIM + i)*L_DIM + j] = p[h];
    }
    return;
  }

  // ========================  PAIR PATH (k_pair_proj)  ======================
  bf16* AsCT = Sh;             // As: 32x136 (LN out) then reused as CT: 128x40 (v^T)
  bf16* Csq  = Sh + 5120;
  bf16* Csk  = Sh + 5120 + 4352;
  bf16* Csg  = Sh + 5120 + 2*4352;
  const int pblk = bid / 3;                            // 0..4607
  const int n = pblk / 12, i0 = (pblk % 12) * 32;
  const int m = lane & 15, q4 = lane >> 4;
  const int rt = wave >> 1, ch = wave & 1;   // row-tile (0/1), col-half (0/1)

  { // LayerNorm -> AsCT (pitch 136)
    const int half = lane >> 5, l32 = lane & 31, c = l32 * 4;
    const float4 g4 = *(const float4*)&lnpg[c];
    const float4 b4 = *(const float4*)&lnpb[c];
    float4 xv[4];
    #pragma unroll
    for (int rr = 0; rr < 4; ++rr) {
      int r = wave*8 + rr*2 + half;
      xv[rr] = *(const float4*)&pair[((size_t)(i0 + r)*L_DIM + n)*DPC + c];
    }
    #pragma unroll
    for (int rr = 0; rr < 4; ++rr) {
      int r = wave*8 + rr*2 + half;
      float s  = xv[rr].x + xv[rr].y + xv[rr].z + xv[rr].w;
      float ss = xv[rr].x*xv[rr].x + xv[rr].y*xv[rr].y + xv[rr].z*xv[rr].z + xv[rr].w*xv[rr].w;
      #pragma unroll
      for (int off = 16; off; off >>= 1) { s += __shfl_xor(s, off, 64); ss += __shfl_xor(ss, off, 64); }
      float mean = s * (1.f/128.f);
      float var  = ss * (1.f/128.f) - mean*mean;
      float rstd = rsqrtf(var + 1e-5f);
      union { bf16 h[4]; bf4_t v; } pk;
      pk.h[0] = f2bf((xv[rr].x-mean)*rstd*g4.x + b4.x);
      pk.h[1] = f2bf((xv[rr].y-mean)*rstd*g4.y + b4.y);
      pk.h[2] = f2bf((xv[rr].z-mean)*rstd*g4.z + b4.z);
      pk.h[3] = f2bf((xv[rr].w-mean)*rstd*g4.w + b4.w);
      *(bf4_t*)&AsCT[r*136 + c] = pk.v;
    }
  }
  __syncthreads();   // B1: As complete

  bf8_t afr[4];
  #pragma unroll
  for (int ks = 0; ks < 4; ++ks)
    afr[ks] = *(const bf8_t*)&AsCT[(rt*16 + m)*136 + ks*32 + q4*8];

  // q, k, gate -> dedicated C-tiles (disjoint from As: no barrier needed)
  const bf16* W3[3] = {Wqp, Wkp, Wgp};
  bf16* C3[3] = {Csq, Csk, Csg};
  #pragma unroll
  for (int s3 = 0; s3 < 3; ++s3) {
    const bf16* Wp = W3[s3];
    bf16* Cs = C3[s3];
    #pragma unroll
    for (int ntl = 0; ntl < 4; ++ntl) {
      const int nt = ch*4 + ntl;
      f4_t acc = {0.f, 0.f, 0.f, 0.f};
      #pragma unroll
      for (int ks = 0; ks < 4; ++ks) {
        bf8_t bfr = *(const bf8_t*)&Wp[(nt*4 + ks)*512 + lane*8];   // L1-hot
        acc = __builtin_amdgcn_mfma_f32_16x16x32_bf16(afr[ks], bfr, acc, 0, 0, 0);
      }
      const int col = nt*16 + m;
      const float bgv = (s3 == 2) ? bg[col] : 0.f;
      #pragma unroll
      for (int reg = 0; reg < 4; ++reg) {
        float v = acc[reg];
        if (s3 == 2) v = 1.f / (1.f + __expf(-(v + bgv)));   // gate sigmoid
        Cs[(rt*16 + q4*4 + reg)*136 + col] = f2bf(v);
      }
    }
  }
  __syncthreads();   // B2: all afr reads done -> safe to overwrite As region with CT

  // v -> CT (As region, pitch 40)
  #pragma unroll
  for (int ntl = 0; ntl < 4; ++ntl) {
    const int nt = ch*4 + ntl;
    f4_t acc = {0.f, 0.f, 0.f, 0.f};
    #pragma unroll
    for (int ks = 0; ks < 4; ++ks) {
      bf8_t bfr = *(const bf8_t*)&Wvp[(nt*4 + ks)*512 + lane*8];
      acc = __builtin_amdgcn_mfma_f32_16x16x32_bf16(afr[ks], bfr, acc, 0, 0, 0);
    }
    const int col = nt*16 + m;
    #pragma unroll
    for (int reg = 0; reg < 4; ++reg)
      AsCT[col*40 + rt*16 + q4*4 + reg] = f2bf(acc[reg]);
  }
  __syncthreads();   // B3: all tiles complete

  // ---- all global stores, fire-and-forget, single drain at kernel end ----
  #pragma unroll
  for (int it = 0; it < 2; ++it) {
    int u = tid + it*256;
    { // v
      int ln = u & 63, dt = (u >> 6) & 1, h = u >> 7;
      bf8_t val = *(const bf8_t*)&AsCT[(h*32 + dt*16 + (ln&15))*40 + (ln>>4)*8];
      size_t dst = ((((size_t)n*NH + h)*12 + (i0>>5))*2 + dt)*512 + (size_t)ln*8;
      *(bf8_t*)&vf[dst] = val;
    }
    { // q, k, gate
      int Il = u >> 8, h = (u >> 6) & 3, ln = u & 63;
      int lidx = (Il*16 + (ln&15))*136 + h*32 + (ln>>4)*8;
      size_t dq = ((((size_t)n*NH + h)*24 + (i0>>4) + Il)*64 + ln)*8;
      *(bf8_t*)&qf[dq] = *(const bf8_t*)&Csq[lidx];
      *(bf8_t*)&kf[dq] = *(const bf8_t*)&Csk[lidx];
      size_t dg = ((((size_t)n*24 + (i0>>4) + Il)*NH + h)*64 + ln)*8;
      *(bf8_t*)&gatef[dg] = *(const bf8_t*)&Csg[lidx];
    }
  }
}

// ---------------------------------------------------------------------------
// Kernel 2: S partials. NSPLIT=8 (48 n/split); Spart bf16, TILED (32 KB/tile,
// 9.4 MB total -> L2/L3 resident round-trip).
__global__ __launch_bounds__(256) void k_qk(
    const bf16* __restrict__ qf, const bf16* __restrict__ kf, bf16* __restrict__ Spart)
{
  const int tid = threadIdx.x, wave = tid >> 6, lane = tid & 63;
  const int m = lane & 15, q4 = lane >> 4;
  const int b = blockIdx.x;
  const int ks = b / 36, rem = b % 36;
  const int h = rem / 9, t9 = rem % 9;
  const int i0 = (t9/3)*128, j0 = (t9%3)*128;
  const int wr = (wave >> 1)*64, wc = (wave & 1)*64;

  f4_t acc[4][4];
  #pragma unroll
  for (int a = 0; a < 4; ++a)
    #pragma unroll
    for (int c = 0; c < 4; ++c) acc[a][c] = (f4_t){0.f,0.f,0.f,0.f};

  const bf16* qp = qf + (((size_t)(ks*48)*NH + h)*24 + ((i0 + wr) >> 4))*512 + (size_t)lane*8;
  const bf16* kp = kf + (((size_t)(ks*48)*NH + h)*24 + ((j0 + wc) >> 4))*512 + (size_t)lane*8;
  const size_t nstride = (size_t)NH*24*512;   // one n step

  bf8_t af[4], bfr[4];
  #pragma unroll
  for (int x = 0; x < 4; ++x) {
    af[x]  = *(const bf8_t*)(qp + x*512);
    bfr[x] = *(const bf8_t*)(kp + x*512);
  }
  #pragma unroll 2
  for (int kt = 0; kt < 48; ++kt) {
    bf8_t afn[4], bfn[4];
    if (kt < 47) {
      const bf16* qn = qp + (size_t)(kt+1)*nstride;
      const bf16* kn = kp + (size_t)(kt+1)*nstride;
      #pragma unroll
      for (int x = 0; x < 4; ++x) {
        afn[x] = *(const bf8_t*)(qn + x*512);
        bfn[x] = *(const bf8_t*)(kn + x*512);
      }
    }
    #pragma unroll
    for (int mt = 0; mt < 4; ++mt)
      #pragma unroll
      for (int nt = 0; nt < 4; ++nt)
        acc[mt][nt] = __builtin_amdgcn_mfma_f32_16x16x32_bf16(af[mt], bfr[nt], acc[mt][nt], 0, 0, 0);
    #pragma unroll
    for (int x = 0; x < 4; ++x) { af[x] = afn[x]; bfr[x] = bfn[x]; }
  }
  // tiled bf16 Spart: tile (ks,h,t9) is contiguous 128*128
  bf16* Sp = Spart + ((size_t)(ks*NH + h)*9 + t9)*16384;
  #pragma unroll
  for (int mt = 0; mt < 4; ++mt)
    #pragma unroll
    for (int nt = 0; nt < 4; ++nt)
      #pragma unroll
      for (int reg = 0; reg < 4; ++reg) {
        int il = wr + mt*16 + q4*4 + reg;     // 0..127 within tile
        int jl = wc + nt*16 + m;              // 0..127 within tile
        Sp[il*128 + jl] = f2bf(acc[mt][nt][reg]);
      }
}

// ---------------------------------------------------------------------------
// Kernel 3: reduce split-K (tiled bf16 Spart), scale, +bias, softmax over j;
// write attn FRAG-MAJOR.
__global__ __launch_bounds__(192) void k_softmax(
    const bf16* __restrict__ Spart, const float* __restrict__ bscore, bf16* __restrict__ attnf)
{
  const int t = threadIdx.x, wave = t >> 6, lane = t & 63;
  const int h = blockIdx.x / L_DIM, i = blockIdx.x % L_DIM;
  const float sc = 0.17677669529663687f / 384.f; // SCALING * (1/L)
  // tiled read: tile = (i>>7)*3 + (j>>7), offset (i&127)*128 + (j&127)
  const size_t toff = ((size_t)((i >> 7)*3 + wave))*16384 + (size_t)(i & 127)*128 + (t & 63)*2;

  float ax = 0.f, ay = 0.f;
  #pragma unroll
  for (int ksp = 0; ksp < NSPLIT; ++ksp) {
    bfu2 p;
    p.u = *(const unsigned*)&Spart[((size_t)(ksp*NH + h)*9)*16384 + toff];
    ax += bf2f(p.h[0]); ay += bf2f(p.h[1]);
  }
  const size_t off = ((size_t)h*L_DIM + i)*L_DIM + t*2;
  const float2 bs = *(const float2*)&bscore[off];
  ax = ax*sc + bs.x;
  ay = ay*sc + bs.y;

  __shared__ float redm[3], reds[3];
  float mx = fmaxf(ax, ay);
  #pragma unroll
  for (int o = 32; o; o >>= 1) mx = fmaxf(mx, __shfl_xor(mx, o, 64));
  if (lane == 0) redm[wave] = mx;
  __syncthreads();
  mx = fmaxf(fmaxf(redm[0], redm[1]), redm[2]);
  float ex = __expf(ax - mx), ey = __expf(ay - mx);
  float sm = ex + ey;
  #pragma unroll
  for (int o = 32; o; o >>= 1) sm += __shfl_xor(sm, o, 64);
  if (lane == 0) reds[wave] = sm;
  __syncthreads();
  const float inv = 1.f / (reds[0] + reds[1] + reds[2]);

  const int j = t*2;
  const int I = i >> 4, mm = i & 15, J = j >> 5, q4 = (j >> 3) & 3, jj = j & 7;
  union { bf16 h2[2]; unsigned u; } pk;
  pk.h2[0] = f2bf(ex * inv);
  pk.h2[1] = f2bf(ey * inv);
  size_t a = ((((size_t)h*24 + I)*12 + J)*64 + q4*16 + mm)*8 + jj;
  *(unsigned*)&attnf[a] = pk.u;
}

// ---------------------------------------------------------------------------
// Kernel 4: PV + gate; all frag-major. Block per (n,h). Gate loads hoisted.
__global__ __launch_bounds__(256) void k_pv(
    const bf16* __restrict__ attnf, const bf16* __restrict__ vf, const bf16* __restrict__ gatef,
    bf16* __restrict__ goutf)
{
  __shared__ __align__(16) bf16 Cs2[384*40];   // [i][d], pad 32->40
  const int tid = threadIdx.x, wave = tid >> 6, lane = tid & 63;
  const int m = lane & 15, q4 = lane >> 4;
  const int n = blockIdx.x >> 2, h = blockIdx.x & 3;

  // hoist HBM-cold gate fragments: overlap the whole MFMA loop
  bf8_t ugp[6];
  #pragma unroll
  for (int it = 0; it < 6; ++it) {
    int u = tid + it*256;
    int I = u >> 6, ln = u & 63;
    ugp[it] = *(const bf8_t*)&gatef[((((size_t)n*24 + I)*NH + h)*64 + ln)*8];
  }

  f4_t acc[6][2];
  #pragma unroll
  for (int a = 0; a < 6; ++a) { acc[a][0] = (f4_t){0,0,0,0}; acc[a][1] = (f4_t){0,0,0,0}; }

  for (int J = 0; J < 12; ++J) {
    const bf16* vb = vf + (((size_t)(n*NH + h)*12 + J)*2)*512;
    bf8_t b0 = *(const bf8_t*)&vb[lane*8];
    bf8_t b1 = *(const bf8_t*)&vb[512 + lane*8];
    #pragma unroll
    for (int mt = 0; mt < 6; ++mt) {
      const int I = wave*6 + mt;
      bf8_t af = *(const bf8_t*)&attnf[(((size_t)h*24 + I)*12 + J)*512 + (size_t)lane*8];
      acc[mt][0] = __builtin_amdgcn_mfma_f32_16x16x32_bf16(af, b0, acc[mt][0], 0, 0, 0);
      acc[mt][1] = __builtin_amdgcn_mfma_f32_16x16x32_bf16(af, b1, acc[mt][1], 0, 0, 0);
    }
  }
  #pragma unroll
  for (int mt = 0; mt < 6; ++mt)
    #pragma unroll
    for (int dt = 0; dt < 2; ++dt)
      #pragma unroll
      for (int reg = 0; reg < 4; ++reg) {
        int i_loc = 16*(wave*6 + mt) + q4*4 + reg;
        Cs2[i_loc*40 + dt*16 + m] = f2bf(acc[mt][dt][reg]);
      }
  __syncthreads();
  #pragma unroll
  for (int it = 0; it < 6; ++it) {
    int u = tid + it*256;
    int I = u >> 6, ln = u & 63;
    bfu8 uc, ug, uo;
    uc.v = *(const bf8_t*)&Cs2[(I*16 + (ln&15))*40 + (ln>>4)*8];
    ug.v = ugp[it];
    #pragma unroll
    for (int e = 0; e < 8; ++e) uo.h[e] = f2bf(bf2f(uc.h[e]) * bf2f(ug.h[e]));
    size_t gidx = ((((size_t)n*24 + I)*NH + h)*64 + ln)*8;
    *(bf8_t*)&goutf[gidx] = uo.v;
  }
}

// ---------------------------------------------------------------------------
// Kernel 5: goutf @ Wo.T + bo -> f32 output, stored transposed: result[i][n][:]
__global__ __launch_bounds__(256) void k_out(
    const bf16* __restrict__ goutf, const bf16* __restrict__ Wop, const float* __restrict__ bo,
    float* __restrict__ outp)
{
  __shared__ __align__(16) float Cs[64][132];
  const int tid = threadIdx.x, wave = tid >> 6, lane = tid & 63;
  const int m = lane & 15, q4 = lane >> 4;
  const int n = blockIdx.x / 6, i0 = (blockIdx.x % 6) * 64;

  bf8_t afr[4];
  #pragma unroll
  for (int ks = 0; ks < 4; ++ks)
    afr[ks] = *(const bf8_t*)&goutf[((((size_t)n*24 + (i0>>4) + wave)*NH + ks)*64 + lane)*8];

  #pragma unroll
  for (int nt = 0; nt < 8; ++nt) {
    f4_t acc = {0.f, 0.f, 0.f, 0.f};
    #pragma unroll
    for (int ks = 0; ks < 4; ++ks) {
      bf8_t bfr = *(const bf8_t*)&Wop[(nt*4 + ks)*512 + lane*8];
      acc = __builtin_amdgcn_mfma_f32_16x16x32_bf16(afr[ks], bfr, acc, 0, 0, 0);
    }
    const int col = nt*16 + m;
    const float bov = bo[col];
    #pragma unroll
    for (int reg = 0; reg < 4; ++reg)
      Cs[wave*16 + q4*4 + reg][col] = acc[reg] + bov;
  }
  __syncthreads();
  for (int u = tid; u < 2048; u += 256) {
    int r = u >> 5, c4 = (u & 31) * 4;
    size_t off = ((size_t)(i0 + r)*L_DIM + n)*DPC + c4;   // transposed store
    *(float4*)&outp[off] = *(const float4*)&Cs[r][c4];
  }
}

// ---------------------------------------------------------------------------
extern "C" void kernel_launch(void* const* d_in, const int* in_sizes, int n_in,
                              void* d_out, int out_size, void* d_ws, size_t ws_size,
                              hipStream_t stream)
{
  (void)in_sizes; (void)n_in; (void)out_size; (void)ws_size;
  const float* pair = (const float*)d_in[0];
  const float* bias = (const float*)d_in[1];
  const float* lnpg = (const float*)d_in[2];
  const float* lnpb = (const float*)d_in[3];
  const float* lnbg = (const float*)d_in[4];
  const float* lnbb = (const float*)d_in[5];
  const float* Wq   = (const float*)d_in[6];
  const float* Wk   = (const float*)d_in[7];
  const float* Wv   = (const float*)d_in[8];
  const float* Wb   = (const float*)d_in[9];
  const float* Wg   = (const float*)d_in[10];
  const float* bg   = (const float*)d_in[11];
  const float* Wo   = (const float*)d_in[12];
  const float* bo   = (const float*)d_in[13];
  float* outp = (float*)d_out;

  char* ws = (char*)d_ws;
  const size_t SZ = (size_t)NROWS * HD * 2;            // 37.75 MB per bf16 tensor
  const size_t SPART_SZ = (size_t)NSPLIT*NH*9*16384*2; // 9.44 MB (bf16, tiled)
  bf16* qfb   = (bf16*)(ws);
  bf16* kfb   = (bf16*)(ws + SZ);
  bf16* vfb   = (bf16*)(ws + 2*SZ);
  bf16* gatef = (bf16*)(ws + 3*SZ);
  float* bscore = (float*)(ws + 4*SZ);
  bf16*  Spart  = (bf16*)(ws + 4*SZ + (size_t)NH*L_DIM*L_DIM*4);
  bf16*  attnf  = (bf16*)(ws + 4*SZ + (size_t)NH*L_DIM*L_DIM*4 + SPART_SZ);
  char*  wb     = ws + 4*SZ + (size_t)NH*L_DIM*L_DIM*4 + SPART_SZ
                     + (size_t)NH*L_DIM*L_DIM*2;
  bf16* Wqp = (bf16*)(wb);
  bf16* Wkp = (bf16*)(wb + 32768);
  bf16* Wvp = (bf16*)(wb + 65536);
  bf16* Wgp = (bf16*)(wb + 98304);
  bf16* Wop = (bf16*)(wb + 131072);
  bf16* goutf = qfb;   // qf dead after k_qk

  hipLaunchKernelGGL(k_prep, dim3(64), dim3(256), 0, stream, Wq, Wk, Wv, Wg, Wo,
                     Wqp, Wkp, Wvp, Wgp, Wop);
  // merged bias+pair projection: 9216 bias blocks + 4608 pair blocks, 2:1 mix
  hipLaunchKernelGGL(k_ln_proj, dim3(13824), dim3(256), 0, stream,
                     pair, lnpg, lnpb, bias, lnbg, lnbb, Wb,
                     Wqp, Wkp, Wvp, Wgp, bg, qfb, kfb, vfb, gatef, bscore);
  hipLaunchKernelGGL(k_qk, dim3(NSPLIT*36), dim3(256), 0, stream, qfb, kfb, Spart);
  hipLaunchKernelGGL(k_softmax, dim3(NH*L_DIM), dim3(192), 0, stream, Spart, bscore, attnf);
  hipLaunchKernelGGL(k_pv, dim3(L_DIM*NH), dim3(256), 0, stream, attnf, vfb, gatef, goutf);
  hipLaunchKernelGGL(k_out, dim3(NROWS/64), dim3(256), 0, stream, goutf, Wop, bo, outp);
}

// Round 8
// 384.594 us; speedup vs baseline: 1.0995x; 1.0995x over previous
//
#include <hip/hip_runtime.h>
#include <hip/hip_bf16.h>

#define L_DIM 384
#define DPC 128
#define NH 4
#define DHD 32
#define HD 128
#define NROWS (L_DIM*L_DIM)
#define NSPLIT 16

typedef __hip_bfloat16 bf16;
typedef __attribute__((ext_vector_type(8))) short bf8_t;   // 8 bf16 (4 VGPRs)
typedef __attribute__((ext_vector_type(4))) short bf4_t;   // 4 bf16 (2 VGPRs)
typedef __attribute__((ext_vector_type(4))) float f4_t;

__device__ __forceinline__ float bf2f(bf16 x){ return __bfloat162float(x); }
__device__ __forceinline__ bf16 f2bf(float x){ return __float2bfloat16(x); }

union bfu8 { bf8_t v; bf16 h[8]; };
union bfu2 { unsigned u; bf16 h[2]; };

// ---------------------------------------------------------------------------
// Kernel 0: f32 weights -> fragment-major bf16 packs.
__global__ __launch_bounds__(256) void k_prep(
    const float* __restrict__ Wq, const float* __restrict__ Wk, const float* __restrict__ Wv,
    const float* __restrict__ Wg, const float* __restrict__ Wo,
    bf16* __restrict__ Wqp, bf16* __restrict__ Wkp, bf16* __restrict__ Wvp,
    bf16* __restrict__ Wgp, bf16* __restrict__ Wop)
{
  const int o = blockIdx.x * 256 + threadIdx.x;   // 64 blocks -> 16384
  const int j = o & 7, lane = (o >> 3) & 63, ks = (o >> 9) & 3, nt = o >> 11;
  const int src = (nt*16 + (lane & 15))*DPC + ks*32 + (lane >> 4)*8 + j;
  Wqp[o] = f2bf(Wq[src]);
  Wkp[o] = f2bf(Wk[src]);
  Wvp[o] = f2bf(Wv[src]);
  Wgp[o] = f2bf(Wg[src]);
  Wop[o] = f2bf(Wo[src]);
}

// ---------------------------------------------------------------------------
// Kernel 1b: LN(bias) + Wb -> bscore[h][i][j] (f32). 16 lanes/row, 4 rows/wave.
__global__ __launch_bounds__(256) void k_bias_proj(
    const float* __restrict__ bias, const float* __restrict__ lng, const float* __restrict__ lnb,
    const float* __restrict__ Wb, float* __restrict__ bscore)
{
  const int tid = threadIdx.x;
  const int wave = tid >> 6, lane = tid & 63;
  const int sub = lane >> 4, l16 = lane & 15, c = l16 * 8;
  const int t = blockIdx.x * 16 + wave * 4 + sub;    // memory row of bias
  const int j = t / L_DIM, i = t % L_DIM;            // bsrc[i][j] = bias row t

  const float4 ga = *(const float4*)&lng[c], gb = *(const float4*)&lng[c+4];
  const float4 ba = *(const float4*)&lnb[c], bb = *(const float4*)&lnb[c+4];
  const float4 xa = *(const float4*)&bias[(size_t)t * DPC + c];
  const float4 xb = *(const float4*)&bias[(size_t)t * DPC + c + 4];

  float s  = xa.x+xa.y+xa.z+xa.w + xb.x+xb.y+xb.z+xb.w;
  float ss = xa.x*xa.x+xa.y*xa.y+xa.z*xa.z+xa.w*xa.w
           + xb.x*xb.x+xb.y*xb.y+xb.z*xb.z+xb.w*xb.w;
  #pragma unroll
  for (int off = 8; off; off >>= 1) { s += __shfl_xor(s, off, 64); ss += __shfl_xor(ss, off, 64); }
  const float mean = s * (1.f/128.f);
  const float var  = ss * (1.f/128.f) - mean*mean;
  const float rstd = rsqrtf(var + 1e-5f);
  float y[8];
  y[0]=(xa.x-mean)*rstd*ga.x+ba.x; y[1]=(xa.y-mean)*rstd*ga.y+ba.y;
  y[2]=(xa.z-mean)*rstd*ga.z+ba.z; y[3]=(xa.w-mean)*rstd*ga.w+ba.w;
  y[4]=(xb.x-mean)*rstd*gb.x+bb.x; y[5]=(xb.y-mean)*rstd*gb.y+bb.y;
  y[6]=(xb.z-mean)*rstd*gb.z+bb.z; y[7]=(xb.w-mean)*rstd*gb.w+bb.w;

  float p[4];
  #pragma unroll
  for (int h = 0; h < 4; ++h) {
    const float4 wa = *(const float4*)&Wb[h*DPC + c];
    const float4 wb4 = *(const float4*)&Wb[h*DPC + c + 4];
    p[h] = y[0]*wa.x + y[1]*wa.y + y[2]*wa.z + y[3]*wa.w
         + y[4]*wb4.x + y[5]*wb4.y + y[6]*wb4.z + y[7]*wb4.w;
    #pragma unroll
    for (int off = 8; off; off >>= 1) p[h] += __shfl_xor(p[h], off, 64);
  }
  if (l16 == 0) {
    #pragma unroll
    for (int h = 0; h < 4; ++h)
      bscore[((size_t)h*L_DIM + i)*L_DIM + j] = p[h];
  }
}

// ---------------------------------------------------------------------------
// Kernel 1: LN(pair^T) + Q/K/V/G projections. 32 rows/block (round-0 best).
__global__ __launch_bounds__(256) void k_pair_proj(
    const float* __restrict__ pair, const float* __restrict__ lng, const float* __restrict__ lnb,
    const bf16* __restrict__ Wqp, const bf16* __restrict__ Wkp, const bf16* __restrict__ Wvp,
    const bf16* __restrict__ Wgp, const float* __restrict__ bg,
    bf16* __restrict__ qf, bf16* __restrict__ kf, bf16* __restrict__ vf, bf16* __restrict__ gatef)
{
  __shared__ __align__(16) bf16 Sh[5120 + 3*4352];
  bf16* AsCT = Sh;             // As: 32x136 (LN out) then reused as CT: 128x40 (v^T)
  bf16* Csq  = Sh + 5120;
  bf16* Csk  = Sh + 5120 + 4352;
  bf16* Csg  = Sh + 5120 + 2*4352;
  const int tid = threadIdx.x;
  const int wave = tid >> 6, lane = tid & 63;
  const int n = blockIdx.x / 12, i0 = (blockIdx.x % 12) * 32;
  const int m = lane & 15, q4 = lane >> 4;
  const int rt = wave >> 1, ch = wave & 1;   // row-tile (0/1), col-half (0/1)

  { // LayerNorm -> AsCT (pitch 136)
    const int half = lane >> 5, l32 = lane & 31, c = l32 * 4;
    const float4 g4 = *(const float4*)&lng[c];
    const float4 b4 = *(const float4*)&lnb[c];
    float4 xv[4];
    #pragma unroll
    for (int rr = 0; rr < 4; ++rr) {
      int r = wave*8 + rr*2 + half;
      xv[rr] = *(const float4*)&pair[((size_t)(i0 + r)*L_DIM + n)*DPC + c];
    }
    #pragma unroll
    for (int rr = 0; rr < 4; ++rr) {
      int r = wave*8 + rr*2 + half;
      float s  = xv[rr].x + xv[rr].y + xv[rr].z + xv[rr].w;
      float ss = xv[rr].x*xv[rr].x + xv[rr].y*xv[rr].y + xv[rr].z*xv[rr].z + xv[rr].w*xv[rr].w;
      #pragma unroll
      for (int off = 16; off; off >>= 1) { s += __shfl_xor(s, off, 64); ss += __shfl_xor(ss, off, 64); }
      float mean = s * (1.f/128.f);
      float var  = ss * (1.f/128.f) - mean*mean;
      float rstd = rsqrtf(var + 1e-5f);
      union { bf16 h[4]; bf4_t v; } pk;
      pk.h[0] = f2bf((xv[rr].x-mean)*rstd*g4.x + b4.x);
      pk.h[1] = f2bf((xv[rr].y-mean)*rstd*g4.y + b4.y);
      pk.h[2] = f2bf((xv[rr].z-mean)*rstd*g4.z + b4.z);
      pk.h[3] = f2bf((xv[rr].w-mean)*rstd*g4.w + b4.w);
      *(bf4_t*)&AsCT[r*136 + c] = pk.v;
    }
  }
  __syncthreads();   // B1: As complete

  bf8_t afr[4];
  #pragma unroll
  for (int ks = 0; ks < 4; ++ks)
    afr[ks] = *(const bf8_t*)&AsCT[(rt*16 + m)*136 + ks*32 + q4*8];

  // q, k, gate -> dedicated C-tiles (disjoint from As: no barrier needed)
  const bf16* W3[3] = {Wqp, Wkp, Wgp};
  bf16* C3[3] = {Csq, Csk, Csg};
  #pragma unroll
  for (int s3 = 0; s3 < 3; ++s3) {
    const bf16* Wp = W3[s3];
    bf16* Cs = C3[s3];
    #pragma unroll
    for (int ntl = 0; ntl < 4; ++ntl) {
      const int nt = ch*4 + ntl;
      f4_t acc = {0.f, 0.f, 0.f, 0.f};
      #pragma unroll
      for (int ks = 0; ks < 4; ++ks) {
        bf8_t bfr = *(const bf8_t*)&Wp[(nt*4 + ks)*512 + lane*8];   // L1-hot
        acc = __builtin_amdgcn_mfma_f32_16x16x32_bf16(afr[ks], bfr, acc, 0, 0, 0);
      }
      const int col = nt*16 + m;
      const float bgv = (s3 == 2) ? bg[col] : 0.f;
      #pragma unroll
      for (int reg = 0; reg < 4; ++reg) {
        float v = acc[reg];
        if (s3 == 2) v = 1.f / (1.f + __expf(-(v + bgv)));   // gate sigmoid
        Cs[(rt*16 + q4*4 + reg)*136 + col] = f2bf(v);
      }
    }
  }
  __syncthreads();   // B2: all afr reads done -> safe to overwrite As region with CT

  // v -> CT (As region, pitch 40)
  #pragma unroll
  for (int ntl = 0; ntl < 4; ++ntl) {
    const int nt = ch*4 + ntl;
    f4_t acc = {0.f, 0.f, 0.f, 0.f};
    #pragma unroll
    for (int ks = 0; ks < 4; ++ks) {
      bf8_t bfr = *(const bf8_t*)&Wvp[(nt*4 + ks)*512 + lane*8];
      acc = __builtin_amdgcn_mfma_f32_16x16x32_bf16(afr[ks], bfr, acc, 0, 0, 0);
    }
    const int col = nt*16 + m;
    #pragma unroll
    for (int reg = 0; reg < 4; ++reg)
      AsCT[col*40 + rt*16 + q4*4 + reg] = f2bf(acc[reg]);
  }
  __syncthreads();   // B3: all tiles complete

  // ---- all global stores, fire-and-forget, single drain at kernel end ----
  #pragma unroll
  for (int it = 0; it < 2; ++it) {
    int u = tid + it*256;
    { // v
      int ln = u & 63, dt = (u >> 6) & 1, h = u >> 7;
      bf8_t val = *(const bf8_t*)&AsCT[(h*32 + dt*16 + (ln&15))*40 + (ln>>4)*8];
      size_t dst = ((((size_t)n*NH + h)*12 + (i0>>5))*2 + dt)*512 + (size_t)ln*8;
      *(bf8_t*)&vf[dst] = val;
    }
    { // q, k, gate
      int Il = u >> 8, h = (u >> 6) & 3, ln = u & 63;
      int lidx = (Il*16 + (ln&15))*136 + h*32 + (ln>>4)*8;
      size_t dq = ((((size_t)n*NH + h)*24 + (i0>>4) + Il)*64 + ln)*8;
      *(bf8_t*)&qf[dq] = *(const bf8_t*)&Csq[lidx];
      *(bf8_t*)&kf[dq] = *(const bf8_t*)&Csk[lidx];
      size_t dg = ((((size_t)n*24 + (i0>>4) + Il)*NH + h)*64 + ln)*8;
      *(bf8_t*)&gatef[dg] = *(const bf8_t*)&Csg[lidx];
    }
  }
}

// ---------------------------------------------------------------------------
// Kernel 2: S partials. NSPLIT=16 (24 n/split, 576 blocks = 2.25/CU for load
// balance); Spart bf16, TILED (32 KB/tile, 18.9 MB total -> L2/L3 resident).
__global__ __launch_bounds__(256) void k_qk(
    const bf16* __restrict__ qf, const bf16* __restrict__ kf, bf16* __restrict__ Spart)
{
  const int tid = threadIdx.x, wave = tid >> 6, lane = tid & 63;
  const int m = lane & 15, q4 = lane >> 4;
  const int b = blockIdx.x;
  const int ks = b / 36, rem = b % 36;
  const int h = rem / 9, t9 = rem % 9;
  const int i0 = (t9/3)*128, j0 = (t9%3)*128;
  const int wr = (wave >> 1)*64, wc = (wave & 1)*64;

  f4_t acc[4][4];
  #pragma unroll
  for (int a = 0; a < 4; ++a)
    #pragma unroll
    for (int c = 0; c < 4; ++c) acc[a][c] = (f4_t){0.f,0.f,0.f,0.f};

  const bf16* qp = qf + (((size_t)(ks*24)*NH + h)*24 + ((i0 + wr) >> 4))*512 + (size_t)lane*8;
  const bf16* kp = kf + (((size_t)(ks*24)*NH + h)*24 + ((j0 + wc) >> 4))*512 + (size_t)lane*8;
  const size_t nstride = (size_t)NH*24*512;   // one n step

  bf8_t af[4], bfr[4];
  #pragma unroll
  for (int x = 0; x < 4; ++x) {
    af[x]  = *(const bf8_t*)(qp + x*512);
    bfr[x] = *(const bf8_t*)(kp + x*512);
  }
  #pragma unroll 2
  for (int kt = 0; kt < 24; ++kt) {
    bf8_t afn[4], bfn[4];
    if (kt < 23) {
      const bf16* qn = qp + (size_t)(kt+1)*nstride;
      const bf16* kn = kp + (size_t)(kt+1)*nstride;
      #pragma unroll
      for (int x = 0; x < 4; ++x) {
        afn[x] = *(const bf8_t*)(qn + x*512);
        bfn[x] = *(const bf8_t*)(kn + x*512);
      }
    }
    #pragma unroll
    for (int mt = 0; mt < 4; ++mt)
      #pragma unroll
      for (int nt = 0; nt < 4; ++nt)
        acc[mt][nt] = __builtin_amdgcn_mfma_f32_16x16x32_bf16(af[mt], bfr[nt], acc[mt][nt], 0, 0, 0);
    #pragma unroll
    for (int x = 0; x < 4; ++x) { af[x] = afn[x]; bfr[x] = bfn[x]; }
  }
  // tiled bf16 Spart: tile (ks,h,t9) is contiguous 128*128
  bf16* Sp = Spart + ((size_t)(ks*NH + h)*9 + t9)*16384;
  #pragma unroll
  for (int mt = 0; mt < 4; ++mt)
    #pragma unroll
    for (int nt = 0; nt < 4; ++nt)
      #pragma unroll
      for (int reg = 0; reg < 4; ++reg) {
        int il = wr + mt*16 + q4*4 + reg;     // 0..127 within tile
        int jl = wc + nt*16 + m;              // 0..127 within tile
        Sp[il*128 + jl] = f2bf(acc[mt][nt][reg]);
      }
}

// ---------------------------------------------------------------------------
// Kernel 3: reduce split-K (tiled bf16 Spart), scale, +bias, softmax over j;
// write attn FRAG-MAJOR.
__global__ __launch_bounds__(192) void k_softmax(
    const bf16* __restrict__ Spart, const float* __restrict__ bscore, bf16* __restrict__ attnf)
{
  const int t = threadIdx.x, wave = t >> 6, lane = t & 63;
  const int h = blockIdx.x / L_DIM, i = blockIdx.x % L_DIM;
  const float sc = 0.17677669529663687f / 384.f; // SCALING * (1/L)
  // tiled read: tile = (i>>7)*3 + (j>>7), offset (i&127)*128 + (j&127)
  const size_t toff = ((size_t)((i >> 7)*3 + wave))*16384 + (size_t)(i & 127)*128 + (t & 63)*2;

  float ax = 0.f, ay = 0.f;
  #pragma unroll
  for (int ksp = 0; ksp < NSPLIT; ++ksp) {
    bfu2 p;
    p.u = *(const unsigned*)&Spart[((size_t)(ksp*NH + h)*9)*16384 + toff];
    ax += bf2f(p.h[0]); ay += bf2f(p.h[1]);
  }
  const size_t off = ((size_t)h*L_DIM + i)*L_DIM + t*2;
  const float2 bs = *(const float2*)&bscore[off];
  ax = ax*sc + bs.x;
  ay = ay*sc + bs.y;

  __shared__ float redm[3], reds[3];
  float mx = fmaxf(ax, ay);
  #pragma unroll
  for (int o = 32; o; o >>= 1) mx = fmaxf(mx, __shfl_xor(mx, o, 64));
  if (lane == 0) redm[wave] = mx;
  __syncthreads();
  mx = fmaxf(fmaxf(redm[0], redm[1]), redm[2]);
  float ex = __expf(ax - mx), ey = __expf(ay - mx);
  float sm = ex + ey;
  #pragma unroll
  for (int o = 32; o; o >>= 1) sm += __shfl_xor(sm, o, 64);
  if (lane == 0) reds[wave] = sm;
  __syncthreads();
  const float inv = 1.f / (reds[0] + reds[1] + reds[2]);

  const int j = t*2;
  const int I = i >> 4, mm = i & 15, J = j >> 5, q4 = (j >> 3) & 3, jj = j & 7;
  union { bf16 h2[2]; unsigned u; } pk;
  pk.h2[0] = f2bf(ex * inv);
  pk.h2[1] = f2bf(ey * inv);
  size_t a = ((((size_t)h*24 + I)*12 + J)*64 + q4*16 + mm)*8 + jj;
  *(unsigned*)&attnf[a] = pk.u;
}

// ---------------------------------------------------------------------------
// Kernel 4: PV + gate; all frag-major. Block per (n,h). Gate loads hoisted.
__global__ __launch_bounds__(256) void k_pv(
    const bf16* __restrict__ attnf, const bf16* __restrict__ vf, const bf16* __restrict__ gatef,
    bf16* __restrict__ goutf)
{
  __shared__ __align__(16) bf16 Cs2[384*40];   // [i][d], pad 32->40
  const int tid = threadIdx.x, wave = tid >> 6, lane = tid & 63;
  const int m = lane & 15, q4 = lane >> 4;
  const int n = blockIdx.x >> 2, h = blockIdx.x & 3;

  // hoist HBM-cold gate fragments: overlap the whole MFMA loop
  bf8_t ugp[6];
  #pragma unroll
  for (int it = 0; it < 6; ++it) {
    int u = tid + it*256;
    int I = u >> 6, ln = u & 63;
    ugp[it] = *(const bf8_t*)&gatef[((((size_t)n*24 + I)*NH + h)*64 + ln)*8];
  }

  f4_t acc[6][2];
  #pragma unroll
  for (int a = 0; a < 6; ++a) { acc[a][0] = (f4_t){0,0,0,0}; acc[a][1] = (f4_t){0,0,0,0}; }

  for (int J = 0; J < 12; ++J) {
    const bf16* vb = vf + (((size_t)(n*NH + h)*12 + J)*2)*512;
    bf8_t b0 = *(const bf8_t*)&vb[lane*8];
    bf8_t b1 = *(const bf8_t*)&vb[512 + lane*8];
    #pragma unroll
    for (int mt = 0; mt < 6; ++mt) {
      const int I = wave*6 + mt;
      bf8_t af = *(const bf8_t*)&attnf[(((size_t)h*24 + I)*12 + J)*512 + (size_t)lane*8];
      acc[mt][0] = __builtin_amdgcn_mfma_f32_16x16x32_bf16(af, b0, acc[mt][0], 0, 0, 0);
      acc[mt][1] = __builtin_amdgcn_mfma_f32_16x16x32_bf16(af, b1, acc[mt][1], 0, 0, 0);
    }
  }
  #pragma unroll
  for (int mt = 0; mt < 6; ++mt)
    #pragma unroll
    for (int dt = 0; dt < 2; ++dt)
      #pragma unroll
      for (int reg = 0; reg < 4; ++reg) {
        int i_loc = 16*(wave*6 + mt) + q4*4 + reg;
        Cs2[i_loc*40 + dt*16 + m] = f2bf(acc[mt][dt][reg]);
      }
  __syncthreads();
  #pragma unroll
  for (int it = 0; it < 6; ++it) {
    int u = tid + it*256;
    int I = u >> 6, ln = u & 63;
    bfu8 uc, ug, uo;
    uc.v = *(const bf8_t*)&Cs2[(I*16 + (ln&15))*40 + (ln>>4)*8];
    ug.v = ugp[it];
    #pragma unroll
    for (int e = 0; e < 8; ++e) uo.h[e] = f2bf(bf2f(uc.h[e]) * bf2f(ug.h[e]));
    size_t gidx = ((((size_t)n*24 + I)*NH + h)*64 + ln)*8;
    *(bf8_t*)&goutf[gidx] = uo.v;
  }
}

// ---------------------------------------------------------------------------
// Kernel 5: goutf @ Wo.T + bo -> f32 output, stored transposed: result[i][n][:]
__global__ __launch_bounds__(256) void k_out(
    const bf16* __restrict__ goutf, const bf16* __restrict__ Wop, const float* __restrict__ bo,
    float* __restrict__ outp)
{
  __shared__ __align__(16) float Cs[64][132];
  const int tid = threadIdx.x, wave = tid >> 6, lane = tid & 63;
  const int m = lane & 15, q4 = lane >> 4;
  const int n = blockIdx.x / 6, i0 = (blockIdx.x % 6) * 64;

  bf8_t afr[4];
  #pragma unroll
  for (int ks = 0; ks < 4; ++ks)
    afr[ks] = *(const bf8_t*)&goutf[((((size_t)n*24 + (i0>>4) + wave)*NH + ks)*64 + lane)*8];

  #pragma unroll
  for (int nt = 0; nt < 8; ++nt) {
    f4_t acc = {0.f, 0.f, 0.f, 0.f};
    #pragma unroll
    for (int ks = 0; ks < 4; ++ks) {
      bf8_t bfr = *(const bf8_t*)&Wop[(nt*4 + ks)*512 + lane*8];
      acc = __builtin_amdgcn_mfma_f32_16x16x32_bf16(afr[ks], bfr, acc, 0, 0, 0);
    }
    const int col = nt*16 + m;
    const float bov = bo[col];
    #pragma unroll
    for (int reg = 0; reg < 4; ++reg)
      Cs[wave*16 + q4*4 + reg][col] = acc[reg] + bov;
  }
  __syncthreads();
  for (int u = tid; u < 2048; u += 256) {
    int r = u >> 5, c4 = (u & 31) * 4;
    size_t off = ((size_t)(i0 + r)*L_DIM + n)*DPC + c4;   // transposed store
    *(float4*)&outp[off] = *(const float4*)&Cs[r][c4];
  }
}

// ---------------------------------------------------------------------------
extern "C" void kernel_launch(void* const* d_in, const int* in_sizes, int n_in,
                              void* d_out, int out_size, void* d_ws, size_t ws_size,
                              hipStream_t stream)
{
  (void)in_sizes; (void)n_in; (void)out_size; (void)ws_size;
  const float* pair = (const float*)d_in[0];
  const float* bias = (const float*)d_in[1];
  const float* lnpg = (const float*)d_in[2];
  const float* lnpb = (const float*)d_in[3];
  const float* lnbg = (const float*)d_in[4];
  const float* lnbb = (const float*)d_in[5];
  const float* Wq   = (const float*)d_in[6];
  const float* Wk   = (const float*)d_in[7];
  const float* Wv   = (const float*)d_in[8];
  const float* Wb   = (const float*)d_in[9];
  const float* Wg   = (const float*)d_in[10];
  const float* bg   = (const float*)d_in[11];
  const float* Wo   = (const float*)d_in[12];
  const float* bo   = (const float*)d_in[13];
  float* outp = (float*)d_out;

  char* ws = (char*)d_ws;
  const size_t SZ = (size_t)NROWS * HD * 2;            // 37.75 MB per bf16 tensor
  const size_t SPART_SZ = (size_t)NSPLIT*NH*9*16384*2; // 18.9 MB (bf16, tiled)
  bf16* qfb   = (bf16*)(ws);
  bf16* kfb   = (bf16*)(ws + SZ);
  bf16* vfb   = (bf16*)(ws + 2*SZ);
  bf16* gatef = (bf16*)(ws + 3*SZ);
  float* bscore = (float*)(ws + 4*SZ);
  bf16*  Spart  = (bf16*)(ws + 4*SZ + (size_t)NH*L_DIM*L_DIM*4);
  bf16*  attnf  = (bf16*)(ws + 4*SZ + (size_t)NH*L_DIM*L_DIM*4 + SPART_SZ);
  char*  wb     = ws + 4*SZ + (size_t)NH*L_DIM*L_DIM*4 + SPART_SZ
                     + (size_t)NH*L_DIM*L_DIM*2;
  bf16* Wqp = (bf16*)(wb);
  bf16* Wkp = (bf16*)(wb + 32768);
  bf16* Wvp = (bf16*)(wb + 65536);
  bf16* Wgp = (bf16*)(wb + 98304);
  bf16* Wop = (bf16*)(wb + 131072);
  bf16* goutf = qfb;   // qf dead after k_qk

  hipLaunchKernelGGL(k_prep, dim3(64), dim3(256), 0, stream, Wq, Wk, Wv, Wg, Wo,
                     Wqp, Wkp, Wvp, Wgp, Wop);
  hipLaunchKernelGGL(k_bias_proj, dim3(NROWS/16), dim3(256), 0, stream, bias, lnbg, lnbb, Wb, bscore);
  hipLaunchKernelGGL(k_pair_proj, dim3(NROWS/32), dim3(256), 0, stream, pair, lnpg, lnpb,
                     Wqp, Wkp, Wvp, Wgp, bg, qfb, kfb, vfb, gatef);
  hipLaunchKernelGGL(k_qk, dim3(NSPLIT*36), dim3(256), 0, stream, qfb, kfb, Spart);
  hipLaunchKernelGGL(k_softmax, dim3(NH*L_DIM), dim3(192), 0, stream, Spart, bscore, attnf);
  hipLaunchKernelGGL(k_pv, dim3(L_DIM*NH), dim3(256), 0, stream, attnf, vfb, gatef, goutf);
  hipLaunchKernelGGL(k_out, dim3(NROWS/64), dim3(256), 0, stream, goutf, Wop, bo, outp);
}